// Round 7
// baseline (335.444 us; speedup 1.0000x reference)
//
#include <hip/hip_runtime.h>
#include <hip/hip_bf16.h>
#include <math.h>

#define T_TOK 8192
#define DM 1024
#define DE 512
#define NE 8
#define DFF 4096

// converted-bf16 buffer layout (element offsets)
#define CO_X   0
#define CO_W1  8388608
#define CO_W2  12582912
#define CO_B1  16777216
#define CO_B2  16781312
#define CO_CE  16789504
#define CO_WR  16797696
#define CO_TOT 16805888

// workspace byte offsets
// meta ints: [0]=flag, [16..23]=counts, [32..39]=off, [48..55]=cinv (floats)
#define WS_GATE2 256
#define WS_B32   65792
#define WS_TOP2  262400
#define WS_TOK   295168
#define WS_AE    360704
#define WS_AG    426240
#define WS_INV   491776
#define WS_CONV  557312
#define WS_HC    34169088

typedef __attribute__((ext_vector_type(8))) __bf16 bf16x8;
typedef __attribute__((ext_vector_type(4))) __bf16 bf16x4;
typedef __attribute__((ext_vector_type(4))) unsigned short u16x4;
typedef __attribute__((ext_vector_type(4))) float f32x4;
typedef __attribute__((ext_vector_type(4))) unsigned int u32x4;

__device__ __forceinline__ f32x4 ld4(const void* p, size_t off, int md)
{
  f32x4 r;
  if (md){
    bf16x4 v = *(const bf16x4*)((const __bf16*)p + off);
    #pragma unroll
    for (int j = 0; j < 4; j++) r[j] = (float)v[j];
  } else {
    r = *(const f32x4*)((const float*)p + off);
  }
  return r;
}

// ---- detect dtype (0=fp32,1=bf16) + centroid inv-norms + zero counts/b32 ----
__global__ __launch_bounds__(256) void detect_k(const void* xp, const void* cp,
                                                int* meta, int* b32)
{
  const int tid = threadIdx.x;
  const float* xf = (const float*)xp;
  int ok = 0;
  for (int i = tid; i < 1024; i += 256){
    float a = fabsf(xf[i]);
    if (a > 1e-8f && a < 100.f) ok++;  // NaN compares false
  }
  __shared__ int cnt;
  __shared__ int flg;
  if (tid == 0) cnt = 0;
  __syncthreads();
  atomicAdd(&cnt, ok);
  __syncthreads();
  if (tid == 0){ flg = (cnt > 512) ? 0 : 1; meta[0] = flg; }
  __syncthreads();
  const int md = flg;

  // centroid inverse norms: expert = tid>>5, 32 threads each
  const int e = tid >> 5, i = tid & 31;
  float ss = 0.f;
  for (int j = 0; j < 32; j++){
    size_t d = (size_t)e * DM + i + j * 32;
    float v = md ? (float)((const __bf16*)cp)[d] : ((const float*)cp)[d];
    ss += v * v;
  }
  #pragma unroll
  for (int m = 1; m < 32; m <<= 1) ss += __shfl_xor(ss, m, 64);
  float* cinv = (float*)(meta + 48);   // bytes 192..223: inside meta region
  if (i == 0) cinv[e] = 1.f / fmaxf(sqrtf(ss), 1e-12f);

  b32[tid] = 0;                 // 32 blocks x 8 experts
  if (tid < 8) meta[16 + tid] = 0;
}

// ---------------- fp32 -> bf16 conversion of all params (fp32 mode only) ----
__global__ __launch_bounds__(256) void convert_k(
    const float* __restrict__ x, const float* __restrict__ w1,
    const float* __restrict__ b1, const float* __restrict__ w2,
    const float* __restrict__ b2, const float* __restrict__ ce,
    const float* __restrict__ wr, __bf16* __restrict__ dst,
    const int* __restrict__ meta)
{
  if (meta[0]) return;
  const size_t i = ((size_t)blockIdx.x * 256 + threadIdx.x) * 4;
  const float* src; size_t off;
  if      (i < CO_W1){ src = x;  off = i - CO_X;  }
  else if (i < CO_W2){ src = w1; off = i - CO_W1; }
  else if (i < CO_B1){ src = w2; off = i - CO_W2; }
  else if (i < CO_B2){ src = b1; off = i - CO_B1; }
  else if (i < CO_CE){ src = b2; off = i - CO_B2; }
  else if (i < CO_WR){ src = ce; off = i - CO_CE; }
  else               { src = wr; off = i - CO_WR; }
  f32x4 v = *(const f32x4*)(src + off);
  bf16x4 o;
  #pragma unroll
  for (int j = 0; j < 4; j++) o[j] = (__bf16)v[j];
  *(bf16x4*)(dst + i) = o;
}

// ---- routing: 16 lanes/token, 16 tokens/block; no contended global atomics -
__global__ __launch_bounds__(256) void route_k(
    const void* __restrict__ xp, const void* __restrict__ cp,
    const void* __restrict__ wp, const int* __restrict__ meta,
    float2* __restrict__ gate2, int* __restrict__ top2, int* __restrict__ b32)
{
  const int md = meta[0];
  const float* cinv = (const float*)(meta + 48);
  const int tid = threadIdx.x;
  const int g = tid >> 4, l = tid & 15;
  const int t = blockIdx.x * 16 + g;

  __shared__ int hist[8];
  if (tid < 8) hist[tid] = 0;
  __syncthreads();

  float xx = 0.f, cd[NE], wd[NE];
  #pragma unroll
  for (int e = 0; e < NE; e++){ cd[e] = 0.f; wd[e] = 0.f; }

  const size_t xbase = (size_t)t * DM;
  for (int j = 0; j < 16; j++){
    const int d0 = j * 64 + l * 4;
    f32x4 xv = ld4(xp, xbase + d0, md);
    xx += xv[0]*xv[0] + xv[1]*xv[1] + xv[2]*xv[2] + xv[3]*xv[3];
    #pragma unroll
    for (int e = 0; e < NE; e++){
      f32x4 cv = ld4(cp, (size_t)e * DM + d0, md);
      f32x4 wv = ld4(wp, (size_t)e * DM + d0, md);
      cd[e] += xv[0]*cv[0] + xv[1]*cv[1] + xv[2]*cv[2] + xv[3]*cv[3];
      wd[e] += xv[0]*wv[0] + xv[1]*wv[1] + xv[2]*wv[2] + xv[3]*wv[3];
    }
  }
  // 4-step reduction across the 16-lane group (17 independent chains)
  #pragma unroll
  for (int m = 1; m < 16; m <<= 1){
    xx += __shfl_xor(xx, m, 64);
    #pragma unroll
    for (int e = 0; e < NE; e++){
      cd[e] += __shfl_xor(cd[e], m, 64);
      wd[e] += __shfl_xor(wd[e], m, 64);
    }
  }

  if (l == 0){
    const float rxn = 1.f / fmaxf(sqrtf(xx), 1e-12f);
    float logits[NE];
    #pragma unroll
    for (int e = 0; e < NE; e++) logits[e] = cd[e] * rxn * cinv[e] + wd[e];
    // top-2, reference tie semantics
    float m1 = -1e30f; int i1 = 0;
    #pragma unroll
    for (int e = 0; e < NE; e++) if (logits[e] > m1){ m1 = logits[e]; i1 = e; }
    float m2 = -1e30f; int i2 = (i1 == 0) ? 1 : 0;
    #pragma unroll
    for (int e = 0; e < NE; e++)
      if (e != i1 && logits[e] > m2){ m2 = logits[e]; i2 = e; }
    float denom = 0.f, ex1 = 0.f, ex2 = 0.f;
    #pragma unroll
    for (int e = 0; e < NE; e++){
      if (logits[e] >= m2){
        float ee = expf(logits[e] - m1);
        denom += ee;
        if (e == i1) ex1 = ee;
        if (e == i2) ex2 = ee;
      }
    }
    const float inv = 1.f / denom;
    gate2[t] = make_float2(ex1 * inv, ex2 * inv);
    top2[t] = i1 | (i2 << 8);
    atomicAdd(&hist[i1], 1);
    atomicAdd(&hist[i2], 1);
  }
  __syncthreads();
  if (tid < 8) atomicAdd(&b32[(blockIdx.x >> 4) * 8 + tid], hist[tid]);
}

// ---- offsets: prefix over 32x8 block counts -> bases (in-place) + meta -----
__global__ void offsets_k(int* meta, int* b32)
{
  const int l = threadIdx.x;  // 64 threads, lanes 0..31 active
  int running = 0;
  for (int e = 0; e < NE; e++){
    int v = (l < 32) ? b32[l * 8 + e] : 0;
    int incl = v;
    #pragma unroll
    for (int ofs = 1; ofs < 32; ofs <<= 1){
      int n = __shfl_up(incl, ofs, 64);
      if (l >= ofs) incl += n;
    }
    int tot = __shfl(incl, 31, 64);
    if (l < 32) b32[l * 8 + e] = running + (incl - v);  // base for (block l, e)
    if (l == 0){ meta[16 + e] = tot; meta[32 + e] = running; }
    running += tot;
  }
}

// ---- placement via block-local LDS cursors (no contended global atomics) ---
__global__ __launch_bounds__(256) void place_k(
    const int* __restrict__ top2, const float2* __restrict__ gate2,
    const int* __restrict__ b32, int* __restrict__ tok, int* __restrict__ ae,
    float* __restrict__ agv, int* __restrict__ inv)
{
  __shared__ int cur[8];
  if (threadIdx.x < 8) cur[threadIdx.x] = b32[blockIdx.x * 8 + threadIdx.x];
  __syncthreads();
  const int t = blockIdx.x * 256 + threadIdx.x;
  const int p = top2[t];
  const float2 gg = gate2[t];
  const int e1 = p & 255, e2 = (p >> 8) & 255;
  const int s1 = atomicAdd(&cur[e1], 1);
  tok[s1] = t; ae[s1] = e1; agv[s1] = gg.x; inv[2 * t] = s1;
  const int s2 = atomicAdd(&cur[e2], 1);
  tok[s2] = t; ae[s2] = e2; agv[s2] = gg.y; inv[2 * t + 1] = s2;
}

// ---- out_init: out[t] = g1*b2[e1] + g2*b2[e2]  (fp32; gemm2 accumulates) ---
__global__ __launch_bounds__(256) void out_init_k(
    const int* __restrict__ top2, const float2* __restrict__ gate2,
    const void* __restrict__ b2q, const int* __restrict__ meta,
    float* __restrict__ out)
{
  const int md = meta[0];
  const size_t idx = ((size_t)blockIdx.x * 256 + threadIdx.x) * 4;
  const int t = (int)(idx >> 10), d = (int)(idx & 1023);
  const int p = top2[t];
  const float2 g = gate2[t];
  const int e1 = p & 255, e2 = (p >> 8) & 255;
  f32x4 bv1 = ld4(b2q, (size_t)e1 * DM + d, md);
  f32x4 bv2 = ld4(b2q, (size_t)e2 * DM + d, md);
  f32x4 r;
  #pragma unroll
  for (int j = 0; j < 4; j++) r[j] = g.x * bv1[j] + g.y * bv2[j];
  *(f32x4*)(out + idx) = r;
}

// block -> (expert, tile) mapping from counts
__device__ __forceinline__ bool find_tile(const int* meta, int tm,
                                          int& e, int& base, int& valid)
{
  for (e = 0; e < NE; e++){
    const int cnt = meta[16 + e];
    const int nt = (cnt + 127) >> 7;
    if (tm < nt){
      const int r0 = tm << 7;
      base = meta[32 + e] + r0;
      valid = cnt - r0;
      return true;
    }
    tm -= nt;
  }
  return false;
}

// ---------------- grouped GEMM1 (128x64 tile): Hc = g*gelu(x@w1_e + b1_e) ---
__global__ __launch_bounds__(256) void gemm1g_k(
    const void* xq, const void* w1q, const void* b1q,
    const __bf16* __restrict__ conv, const int* __restrict__ meta,
    const int* __restrict__ tok, const float* __restrict__ agv,
    __bf16* __restrict__ Hc)
{
  const int md = meta[0];
  const __bf16* X  = md ? (const __bf16*)xq  : conv + CO_X;
  const __bf16* W  = md ? (const __bf16*)w1q : conv + CO_W1;
  const __bf16* bb = md ? (const __bf16*)b1q : conv + CO_B1;

  int e, base, valid;
  if (!find_tile(meta, blockIdx.x, e, base, valid)) return;
  const int n0 = blockIdx.y * 64;

  __shared__ __attribute__((aligned(16))) __bf16 As[128 * 40];
  __shared__ __attribute__((aligned(16))) unsigned int Bs[64 * 20];

  const int tid = threadIdx.x;
  const int wv = tid >> 6, lane = tid & 63;
  const int q = lane >> 4, ln = lane & 15;
  const int wm = (wv & 1) * 64, wn = (wv >> 1) * 32;
  f32x4 acc[4][2] = {};

  const int arow = tid >> 1, aseg = (tid & 1) * 16;
  const int gr = (arow < valid) ? arow : 0;
  const int trow = tok[base + gr];
  const __bf16* Ag = X + (size_t)trow * DM + aseg;

  // B-stage: 32k x 64n; thread: kp=tid&15 (2 k-rows), 4 cols at (tid>>4)*4
  const int bkp = tid & 15, bnc = (tid >> 4) * 4;
  const __bf16* Bg = W + (size_t)e * (DM * DE) + n0 + (size_t)(2 * bkp) * DE + bnc;

  for (int k0 = 0; k0 < DM; k0 += 32){
    *(bf16x8*)&As[arow * 40 + aseg]     = *(const bf16x8*)(Ag + k0);
    *(bf16x8*)&As[arow * 40 + aseg + 8] = *(const bf16x8*)(Ag + k0 + 8);
    bf16x4 r0v = *(const bf16x4*)(Bg + (size_t)k0 * DE);
    bf16x4 r1v = *(const bf16x4*)(Bg + (size_t)k0 * DE + DE);
    u16x4 s0 = __builtin_bit_cast(u16x4, r0v);
    u16x4 s1 = __builtin_bit_cast(u16x4, r1v);
    #pragma unroll
    for (int j = 0; j < 4; j++)
      Bs[(bnc + j) * 20 + bkp] = (unsigned)s0[j] | ((unsigned)s1[j] << 16);
    __syncthreads();

    bf16x8 af[4], bfv[2];
    #pragma unroll
    for (int mi = 0; mi < 4; mi++)
      af[mi] = *(const bf16x8*)&As[(wm + mi * 16 + ln) * 40 + q * 8];
    #pragma unroll
    for (int ni = 0; ni < 2; ni++){
      u32x4 bw = *(const u32x4*)&Bs[(wn + ni * 16 + ln) * 20 + q * 4];
      bfv[ni] = __builtin_bit_cast(bf16x8, bw);
    }
    #pragma unroll
    for (int mi = 0; mi < 4; mi++)
      #pragma unroll
      for (int ni = 0; ni < 2; ni++)
        acc[mi][ni] = __builtin_amdgcn_mfma_f32_16x16x32_bf16(
            af[mi], bfv[ni], acc[mi][ni], 0, 0, 0);
    __syncthreads();
  }

  const int coln = n0 + wn;
  float bset[2];
  #pragma unroll
  for (int ni = 0; ni < 2; ni++)
    bset[ni] = (float)bb[e * DE + coln + ni * 16 + ln];
  #pragma unroll
  for (int mi = 0; mi < 4; mi++){
    #pragma unroll
    for (int r = 0; r < 4; r++){
      const int row = wm + mi * 16 + q * 4 + r;
      if (row < valid){
        const int slot = base + row;
        const float g = agv[slot];
        #pragma unroll
        for (int ni = 0; ni < 2; ni++){
          float v = acc[mi][ni][r] + bset[ni];
          float h = 0.5f * v * (1.0f + erff(v * 0.70710678118654752f));
          Hc[(size_t)slot * DE + coln + ni * 16 + ln] = (__bf16)(g * h);
        }
      }
    }
  }
}

// ------- grouped GEMM2 (128x64 tile): out[tok] += Hc[slot] @ w2_e ----------
__global__ __launch_bounds__(256) void gemm2g_k(
    const __bf16* __restrict__ Hc, const void* w2q,
    const __bf16* __restrict__ conv, const int* __restrict__ meta,
    const int* __restrict__ tok, float* __restrict__ out)
{
  const int md = meta[0];
  const __bf16* W = md ? (const __bf16*)w2q : conv + CO_W2;

  int e, base, valid;
  if (!find_tile(meta, blockIdx.x, e, base, valid)) return;
  const int n0 = blockIdx.y * 64;

  __shared__ __attribute__((aligned(16))) __bf16 As[128 * 40];
  __shared__ __attribute__((aligned(16))) unsigned int Bs[64 * 20];

  const int tid = threadIdx.x;
  const int wv = tid >> 6, lane = tid & 63;
  const int q = lane >> 4, ln = lane & 15;
  const int wm = (wv & 1) * 64, wn = (wv >> 1) * 32;
  f32x4 acc[4][2] = {};

  const int arow = tid >> 1, aseg = (tid & 1) * 16;
  const int gr = (arow < valid) ? arow : 0;
  const __bf16* Ag = Hc + (size_t)(base + gr) * DE + aseg;

  const int bkp = tid & 15, bnc = (tid >> 4) * 4;
  const __bf16* Bg = W + (size_t)e * (DE * DM) + n0 + (size_t)(2 * bkp) * DM + bnc;

  for (int k0 = 0; k0 < DE; k0 += 32){
    *(bf16x8*)&As[arow * 40 + aseg]     = *(const bf16x8*)(Ag + k0);
    *(bf16x8*)&As[arow * 40 + aseg + 8] = *(const bf16x8*)(Ag + k0 + 8);
    bf16x4 r0v = *(const bf16x4*)(Bg + (size_t)k0 * DM);
    bf16x4 r1v = *(const bf16x4*)(Bg + (size_t)k0 * DM + DM);
    u16x4 s0 = __builtin_bit_cast(u16x4, r0v);
    u16x4 s1 = __builtin_bit_cast(u16x4, r1v);
    #pragma unroll
    for (int j = 0; j < 4; j++)
      Bs[(bnc + j) * 20 + bkp] = (unsigned)s0[j] | ((unsigned)s1[j] << 16);
    __syncthreads();

    bf16x8 af[4], bfv[2];
    #pragma unroll
    for (int mi = 0; mi < 4; mi++)
      af[mi] = *(const bf16x8*)&As[(wm + mi * 16 + ln) * 40 + q * 8];
    #pragma unroll
    for (int ni = 0; ni < 2; ni++){
      u32x4 bw = *(const u32x4*)&Bs[(wn + ni * 16 + ln) * 20 + q * 4];
      bfv[ni] = __builtin_bit_cast(bf16x8, bw);
    }
    #pragma unroll
    for (int mi = 0; mi < 4; mi++)
      #pragma unroll
      for (int ni = 0; ni < 2; ni++)
        acc[mi][ni] = __builtin_amdgcn_mfma_f32_16x16x32_bf16(
            af[mi], bfv[ni], acc[mi][ni], 0, 0, 0);
    __syncthreads();
  }

  // epilogue: accumulate into out (each element gets exactly 2 expert adds)
  #pragma unroll
  for (int mi = 0; mi < 4; mi++){
    #pragma unroll
    for (int r = 0; r < 4; r++){
      const int row = wm + mi * 16 + q * 4 + r;
      if (row < valid){
        const int t = tok[base + row];
        #pragma unroll
        for (int ni = 0; ni < 2; ni++)
          atomicAdd(&out[(size_t)t * DM + n0 + wn + ni * 16 + ln],
                    acc[mi][ni][r]);
      }
    }
  }
}

extern "C" void kernel_launch(void* const* d_in, const int* in_sizes, int n_in,
                              void* d_out, int out_size, void* d_ws, size_t ws_size,
                              hipStream_t stream)
{
  char* ws = (char*)d_ws;
  int*    meta  = (int*)ws;
  float2* gate2 = (float2*)(ws + WS_GATE2);
  int*    b32   = (int*)(ws + WS_B32);
  int*    top2  = (int*)(ws + WS_TOP2);
  int*    tok   = (int*)(ws + WS_TOK);
  int*    ae    = (int*)(ws + WS_AE);
  float*  agv   = (float*)(ws + WS_AG);
  int*    inv   = (int*)(ws + WS_INV);
  __bf16* conv  = (__bf16*)(ws + WS_CONV);
  __bf16* Hc    = (__bf16*)(ws + WS_HC);

  detect_k<<<1, 256, 0, stream>>>(d_in[0], d_in[5], meta, b32);
  convert_k<<<CO_TOT / 1024, 256, 0, stream>>>(
      (const float*)d_in[0], (const float*)d_in[1], (const float*)d_in[2],
      (const float*)d_in[3], (const float*)d_in[4], (const float*)d_in[5],
      (const float*)d_in[6], conv, meta);
  route_k<<<T_TOK / 16, 256, 0, stream>>>(d_in[0], d_in[5], d_in[6], meta,
                                          gate2, top2, b32);
  offsets_k<<<1, 64, 0, stream>>>(meta, b32);
  place_k<<<T_TOK / 256, 256, 0, stream>>>(top2, gate2, b32, tok, ae, agv, inv);
  out_init_k<<<T_TOK * DM / 1024, 256, 0, stream>>>(top2, gate2, d_in[4], meta,
                                                    (float*)d_out);
  gemm1g_k<<<dim3(136, 8), 256, 0, stream>>>(d_in[0], d_in[1], d_in[2], conv,
                                             meta, tok, agv, Hc);
  gemm2g_k<<<dim3(136, 16), 256, 0, stream>>>(Hc, d_in[3], conv, meta, tok,
                                              (float*)d_out);
}

// Round 8
// 300.341 us; speedup vs baseline: 1.1169x; 1.1169x over previous
//
#include <hip/hip_runtime.h>
#include <hip/hip_bf16.h>
#include <math.h>

#define T_TOK 8192
#define DM 1024
#define DE 512
#define NE 8
#define DFF 4096

// converted-bf16 buffer layout (element offsets)
#define CO_X   0
#define CO_W1  8388608
#define CO_W2  12582912
#define CO_B1  16777216
#define CO_B2  16781312
#define CO_CE  16789504
#define CO_WR  16797696
#define CO_TOT 16805888

// workspace byte offsets
// meta ints: [0]=flag, [16..23]=counts, [32..39]=off, [48..55]=cinv (floats)
#define WS_GATE2 256
#define WS_B32   65792
#define WS_TOP2  262400
#define WS_TOK   295168
#define WS_AE    360704
#define WS_AG    426240
#define WS_INV   491776
#define WS_CONV  557312
#define WS_HC    34169088
#define WS_OC    50946304

typedef __attribute__((ext_vector_type(8))) __bf16 bf16x8;
typedef __attribute__((ext_vector_type(4))) __bf16 bf16x4;
typedef __attribute__((ext_vector_type(4))) unsigned short u16x4;
typedef __attribute__((ext_vector_type(4))) float f32x4;
typedef __attribute__((ext_vector_type(4))) unsigned int u32x4;

__device__ __forceinline__ f32x4 ld4(const void* p, size_t off, int md)
{
  f32x4 r;
  if (md){
    bf16x4 v = *(const bf16x4*)((const __bf16*)p + off);
    #pragma unroll
    for (int j = 0; j < 4; j++) r[j] = (float)v[j];
  } else {
    r = *(const f32x4*)((const float*)p + off);
  }
  return r;
}

// ---- detect dtype (0=fp32,1=bf16) + centroid inv-norms + zero counts/b32 ----
__global__ __launch_bounds__(256) void detect_k(const void* xp, const void* cp,
                                                int* meta, int* b32)
{
  const int tid = threadIdx.x;
  const float* xf = (const float*)xp;
  int ok = 0;
  for (int i = tid; i < 1024; i += 256){
    float a = fabsf(xf[i]);
    if (a > 1e-8f && a < 100.f) ok++;  // NaN compares false
  }
  __shared__ int cnt;
  __shared__ int flg;
  if (tid == 0) cnt = 0;
  __syncthreads();
  atomicAdd(&cnt, ok);
  __syncthreads();
  if (tid == 0){ flg = (cnt > 512) ? 0 : 1; meta[0] = flg; }
  __syncthreads();
  const int md = flg;

  // centroid inverse norms: expert = tid>>5, 32 threads each
  const int e = tid >> 5, i = tid & 31;
  float ss = 0.f;
  for (int j = 0; j < 32; j++){
    size_t d = (size_t)e * DM + i + j * 32;
    float v = md ? (float)((const __bf16*)cp)[d] : ((const float*)cp)[d];
    ss += v * v;
  }
  #pragma unroll
  for (int m = 1; m < 32; m <<= 1) ss += __shfl_xor(ss, m, 64);
  float* cinv = (float*)(meta + 48);   // bytes 192..223: inside meta region
  if (i == 0) cinv[e] = 1.f / fmaxf(sqrtf(ss), 1e-12f);

  b32[tid] = 0;                 // 32 blocks x 8 experts
  if (tid < 8) meta[16 + tid] = 0;
}

// ---------------- fp32 -> bf16 conversion of all params (fp32 mode only) ----
__global__ __launch_bounds__(256) void convert_k(
    const float* __restrict__ x, const float* __restrict__ w1,
    const float* __restrict__ b1, const float* __restrict__ w2,
    const float* __restrict__ b2, const float* __restrict__ ce,
    const float* __restrict__ wr, __bf16* __restrict__ dst,
    const int* __restrict__ meta)
{
  if (meta[0]) return;
  const size_t i = ((size_t)blockIdx.x * 256 + threadIdx.x) * 4;
  const float* src; size_t off;
  if      (i < CO_W1){ src = x;  off = i - CO_X;  }
  else if (i < CO_W2){ src = w1; off = i - CO_W1; }
  else if (i < CO_B1){ src = w2; off = i - CO_W2; }
  else if (i < CO_B2){ src = b1; off = i - CO_B1; }
  else if (i < CO_CE){ src = b2; off = i - CO_B2; }
  else if (i < CO_WR){ src = ce; off = i - CO_CE; }
  else               { src = wr; off = i - CO_WR; }
  f32x4 v = *(const f32x4*)(src + off);
  bf16x4 o;
  #pragma unroll
  for (int j = 0; j < 4; j++) o[j] = (__bf16)v[j];
  *(bf16x4*)(dst + i) = o;
}

// ---- routing: 16 lanes/token, 16 tokens/block; no contended global atomics -
__global__ __launch_bounds__(256) void route_k(
    const void* __restrict__ xp, const void* __restrict__ cp,
    const void* __restrict__ wp, const int* __restrict__ meta,
    float2* __restrict__ gate2, int* __restrict__ top2, int* __restrict__ b32)
{
  const int md = meta[0];
  const float* cinv = (const float*)(meta + 48);
  const int tid = threadIdx.x;
  const int g = tid >> 4, l = tid & 15;
  const int t = blockIdx.x * 16 + g;

  __shared__ int hist[8];
  if (tid < 8) hist[tid] = 0;
  __syncthreads();

  float xx = 0.f, cd[NE], wd[NE];
  #pragma unroll
  for (int e = 0; e < NE; e++){ cd[e] = 0.f; wd[e] = 0.f; }

  const size_t xbase = (size_t)t * DM;
  for (int j = 0; j < 16; j++){
    const int d0 = j * 64 + l * 4;
    f32x4 xv = ld4(xp, xbase + d0, md);
    xx += xv[0]*xv[0] + xv[1]*xv[1] + xv[2]*xv[2] + xv[3]*xv[3];
    #pragma unroll
    for (int e = 0; e < NE; e++){
      f32x4 cv = ld4(cp, (size_t)e * DM + d0, md);
      f32x4 wv = ld4(wp, (size_t)e * DM + d0, md);
      cd[e] += xv[0]*cv[0] + xv[1]*cv[1] + xv[2]*cv[2] + xv[3]*cv[3];
      wd[e] += xv[0]*wv[0] + xv[1]*wv[1] + xv[2]*wv[2] + xv[3]*wv[3];
    }
  }
  // 4-step reduction across the 16-lane group (17 independent chains)
  #pragma unroll
  for (int m = 1; m < 16; m <<= 1){
    xx += __shfl_xor(xx, m, 64);
    #pragma unroll
    for (int e = 0; e < NE; e++){
      cd[e] += __shfl_xor(cd[e], m, 64);
      wd[e] += __shfl_xor(wd[e], m, 64);
    }
  }

  if (l == 0){
    const float rxn = 1.f / fmaxf(sqrtf(xx), 1e-12f);
    float logits[NE];
    #pragma unroll
    for (int e = 0; e < NE; e++) logits[e] = cd[e] * rxn * cinv[e] + wd[e];
    // top-2, reference tie semantics
    float m1 = -1e30f; int i1 = 0;
    #pragma unroll
    for (int e = 0; e < NE; e++) if (logits[e] > m1){ m1 = logits[e]; i1 = e; }
    float m2 = -1e30f; int i2 = (i1 == 0) ? 1 : 0;
    #pragma unroll
    for (int e = 0; e < NE; e++)
      if (e != i1 && logits[e] > m2){ m2 = logits[e]; i2 = e; }
    float denom = 0.f, ex1 = 0.f, ex2 = 0.f;
    #pragma unroll
    for (int e = 0; e < NE; e++){
      if (logits[e] >= m2){
        float ee = expf(logits[e] - m1);
        denom += ee;
        if (e == i1) ex1 = ee;
        if (e == i2) ex2 = ee;
      }
    }
    const float inv = 1.f / denom;
    gate2[t] = make_float2(ex1 * inv, ex2 * inv);
    top2[t] = i1 | (i2 << 8);
    atomicAdd(&hist[i1], 1);
    atomicAdd(&hist[i2], 1);
  }
  __syncthreads();
  if (tid < 8) atomicAdd(&b32[(blockIdx.x >> 4) * 8 + tid], hist[tid]);
}

// ---- offsets: prefix over 32x8 block counts -> bases (in-place) + meta -----
__global__ void offsets_k(int* meta, int* b32)
{
  const int l = threadIdx.x;  // 64 threads, lanes 0..31 active
  int running = 0;
  for (int e = 0; e < NE; e++){
    int v = (l < 32) ? b32[l * 8 + e] : 0;
    int incl = v;
    #pragma unroll
    for (int ofs = 1; ofs < 32; ofs <<= 1){
      int n = __shfl_up(incl, ofs, 64);
      if (l >= ofs) incl += n;
    }
    int tot = __shfl(incl, 31, 64);
    if (l < 32) b32[l * 8 + e] = running + (incl - v);  // base for (block l, e)
    if (l == 0){ meta[16 + e] = tot; meta[32 + e] = running; }
    running += tot;
  }
}

// ---- placement via block-local LDS cursors (no contended global atomics) ---
__global__ __launch_bounds__(256) void place_k(
    const int* __restrict__ top2, const float2* __restrict__ gate2,
    const int* __restrict__ b32, int* __restrict__ tok, int* __restrict__ ae,
    float* __restrict__ agv, int* __restrict__ inv)
{
  __shared__ int cur[8];
  if (threadIdx.x < 8) cur[threadIdx.x] = b32[blockIdx.x * 8 + threadIdx.x];
  __syncthreads();
  const int t = blockIdx.x * 256 + threadIdx.x;
  const int p = top2[t];
  const float2 gg = gate2[t];
  const int e1 = p & 255, e2 = (p >> 8) & 255;
  const int s1 = atomicAdd(&cur[e1], 1);
  tok[s1] = t; ae[s1] = e1; agv[s1] = gg.x; inv[2 * t] = s1;
  const int s2 = atomicAdd(&cur[e2], 1);
  tok[s2] = t; ae[s2] = e2; agv[s2] = gg.y; inv[2 * t + 1] = s2;
}

// block -> (expert, tile) mapping from counts
__device__ __forceinline__ bool find_tile(const int* meta, int tm,
                                          int& e, int& base, int& valid)
{
  for (e = 0; e < NE; e++){
    const int cnt = meta[16 + e];
    const int nt = (cnt + 127) >> 7;
    if (tm < nt){
      const int r0 = tm << 7;
      base = meta[32 + e] + r0;
      valid = cnt - r0;
      return true;
    }
    tm -= nt;
  }
  return false;
}

// ---------------- grouped GEMM1 (128x64 tile): Hc = g*gelu(x@w1_e + b1_e) ---
__global__ __launch_bounds__(256) void gemm1g_k(
    const void* xq, const void* w1q, const void* b1q,
    const __bf16* __restrict__ conv, const int* __restrict__ meta,
    const int* __restrict__ tok, const float* __restrict__ agv,
    __bf16* __restrict__ Hc)
{
  const int md = meta[0];
  const __bf16* X  = md ? (const __bf16*)xq  : conv + CO_X;
  const __bf16* W  = md ? (const __bf16*)w1q : conv + CO_W1;
  const __bf16* bb = md ? (const __bf16*)b1q : conv + CO_B1;

  int e, base, valid;
  if (!find_tile(meta, blockIdx.x, e, base, valid)) return;
  const int n0 = blockIdx.y * 64;

  __shared__ __attribute__((aligned(16))) __bf16 As[128 * 40];
  __shared__ __attribute__((aligned(16))) unsigned int Bs[64 * 20];

  const int tid = threadIdx.x;
  const int wv = tid >> 6, lane = tid & 63;
  const int q = lane >> 4, ln = lane & 15;
  const int wm = (wv & 1) * 64, wn = (wv >> 1) * 32;
  f32x4 acc[4][2] = {};

  const int arow = tid >> 1, aseg = (tid & 1) * 16;
  const int gr = (arow < valid) ? arow : 0;
  const int trow = tok[base + gr];
  const __bf16* Ag = X + (size_t)trow * DM + aseg;

  // B-stage: 32k x 64n; thread: kp=tid&15 (2 k-rows), 4 cols at (tid>>4)*4
  const int bkp = tid & 15, bnc = (tid >> 4) * 4;
  const __bf16* Bg = W + (size_t)e * (DM * DE) + n0 + (size_t)(2 * bkp) * DE + bnc;

  for (int k0 = 0; k0 < DM; k0 += 32){
    *(bf16x8*)&As[arow * 40 + aseg]     = *(const bf16x8*)(Ag + k0);
    *(bf16x8*)&As[arow * 40 + aseg + 8] = *(const bf16x8*)(Ag + k0 + 8);
    bf16x4 r0v = *(const bf16x4*)(Bg + (size_t)k0 * DE);
    bf16x4 r1v = *(const bf16x4*)(Bg + (size_t)k0 * DE + DE);
    u16x4 s0 = __builtin_bit_cast(u16x4, r0v);
    u16x4 s1 = __builtin_bit_cast(u16x4, r1v);
    #pragma unroll
    for (int j = 0; j < 4; j++)
      Bs[(bnc + j) * 20 + bkp] = (unsigned)s0[j] | ((unsigned)s1[j] << 16);
    __syncthreads();

    bf16x8 af[4], bfv[2];
    #pragma unroll
    for (int mi = 0; mi < 4; mi++)
      af[mi] = *(const bf16x8*)&As[(wm + mi * 16 + ln) * 40 + q * 8];
    #pragma unroll
    for (int ni = 0; ni < 2; ni++){
      u32x4 bw = *(const u32x4*)&Bs[(wn + ni * 16 + ln) * 20 + q * 4];
      bfv[ni] = __builtin_bit_cast(bf16x8, bw);
    }
    #pragma unroll
    for (int mi = 0; mi < 4; mi++)
      #pragma unroll
      for (int ni = 0; ni < 2; ni++)
        acc[mi][ni] = __builtin_amdgcn_mfma_f32_16x16x32_bf16(
            af[mi], bfv[ni], acc[mi][ni], 0, 0, 0);
    __syncthreads();
  }

  const int coln = n0 + wn;
  float bset[2];
  #pragma unroll
  for (int ni = 0; ni < 2; ni++)
    bset[ni] = (float)bb[e * DE + coln + ni * 16 + ln];
  #pragma unroll
  for (int mi = 0; mi < 4; mi++){
    #pragma unroll
    for (int r = 0; r < 4; r++){
      const int row = wm + mi * 16 + q * 4 + r;
      if (row < valid){
        const int slot = base + row;
        const float g = agv[slot];
        #pragma unroll
        for (int ni = 0; ni < 2; ni++){
          float v = acc[mi][ni][r] + bset[ni];
          float h = 0.5f * v * (1.0f + erff(v * 0.70710678118654752f));
          Hc[(size_t)slot * DE + coln + ni * 16 + ln] = (__bf16)(g * h);
        }
      }
    }
  }
}

// ------- grouped GEMM2 (128x64 tile): Oc[slot][d] = Hc[slot] @ w2_e ---------
__global__ __launch_bounds__(256) void gemm2g_k(
    const __bf16* __restrict__ Hc, const void* w2q,
    const __bf16* __restrict__ conv, const int* __restrict__ meta,
    __bf16* __restrict__ Oc)
{
  const int md = meta[0];
  const __bf16* W = md ? (const __bf16*)w2q : conv + CO_W2;

  int e, base, valid;
  if (!find_tile(meta, blockIdx.x, e, base, valid)) return;
  const int n0 = blockIdx.y * 64;

  __shared__ __attribute__((aligned(16))) __bf16 As[128 * 40];
  __shared__ __attribute__((aligned(16))) unsigned int Bs[64 * 20];

  const int tid = threadIdx.x;
  const int wv = tid >> 6, lane = tid & 63;
  const int q = lane >> 4, ln = lane & 15;
  const int wm = (wv & 1) * 64, wn = (wv >> 1) * 32;
  f32x4 acc[4][2] = {};

  const int arow = tid >> 1, aseg = (tid & 1) * 16;
  const int gr = (arow < valid) ? arow : 0;
  const __bf16* Ag = Hc + (size_t)(base + gr) * DE + aseg;

  const int bkp = tid & 15, bnc = (tid >> 4) * 4;
  const __bf16* Bg = W + (size_t)e * (DE * DM) + n0 + (size_t)(2 * bkp) * DM + bnc;

  for (int k0 = 0; k0 < DE; k0 += 32){
    *(bf16x8*)&As[arow * 40 + aseg]     = *(const bf16x8*)(Ag + k0);
    *(bf16x8*)&As[arow * 40 + aseg + 8] = *(const bf16x8*)(Ag + k0 + 8);
    bf16x4 r0v = *(const bf16x4*)(Bg + (size_t)k0 * DM);
    bf16x4 r1v = *(const bf16x4*)(Bg + (size_t)k0 * DM + DM);
    u16x4 s0 = __builtin_bit_cast(u16x4, r0v);
    u16x4 s1 = __builtin_bit_cast(u16x4, r1v);
    #pragma unroll
    for (int j = 0; j < 4; j++)
      Bs[(bnc + j) * 20 + bkp] = (unsigned)s0[j] | ((unsigned)s1[j] << 16);
    __syncthreads();

    bf16x8 af[4], bfv[2];
    #pragma unroll
    for (int mi = 0; mi < 4; mi++)
      af[mi] = *(const bf16x8*)&As[(wm + mi * 16 + ln) * 40 + q * 8];
    #pragma unroll
    for (int ni = 0; ni < 2; ni++){
      u32x4 bw = *(const u32x4*)&Bs[(wn + ni * 16 + ln) * 20 + q * 4];
      bfv[ni] = __builtin_bit_cast(bf16x8, bw);
    }
    #pragma unroll
    for (int mi = 0; mi < 4; mi++)
      #pragma unroll
      for (int ni = 0; ni < 2; ni++)
        acc[mi][ni] = __builtin_amdgcn_mfma_f32_16x16x32_bf16(
            af[mi], bfv[ni], acc[mi][ni], 0, 0, 0);
    __syncthreads();
  }

  #pragma unroll
  for (int mi = 0; mi < 4; mi++){
    #pragma unroll
    for (int r = 0; r < 4; r++){
      const int row = wm + mi * 16 + q * 4 + r;
      if (row < valid){
        const int slot = base + row;
        #pragma unroll
        for (int ni = 0; ni < 2; ni++)
          Oc[(size_t)slot * DM + n0 + wn + ni * 16 + ln] = (__bf16)acc[mi][ni][r];
      }
    }
  }
}

// ---------------- combine: out[t] = Oc[s1] + Oc[s2] + g1*b2[e1] + g2*b2[e2] -
__global__ __launch_bounds__(256) void combine_k(
    const __bf16* __restrict__ Oc, const int* __restrict__ inv,
    const int* __restrict__ ae, const float* __restrict__ agv,
    const void* b2q, const int* __restrict__ meta, void* out)
{
  const int md = meta[0];
  const int t = blockIdx.x;
  const int s1 = inv[2 * t], s2 = inv[2 * t + 1];
  const int e1 = ae[s1], e2 = ae[s2];
  const float g1 = agv[s1], g2 = agv[s2];
  const int c = threadIdx.x * 4;

  bf16x4 o1 = *(const bf16x4*)(Oc + (size_t)s1 * DM + c);
  bf16x4 o2 = *(const bf16x4*)(Oc + (size_t)s2 * DM + c);
  float b1v[4], b2v[4];
  if (md){
    const __bf16* B2 = (const __bf16*)b2q;
    bf16x4 a = *(const bf16x4*)(B2 + e1 * DM + c);
    bf16x4 b = *(const bf16x4*)(B2 + e2 * DM + c);
    #pragma unroll
    for (int j = 0; j < 4; j++){ b1v[j] = (float)a[j]; b2v[j] = (float)b[j]; }
  } else {
    const float* B2 = (const float*)b2q;
    f32x4 a = *(const f32x4*)(B2 + e1 * DM + c);
    f32x4 b = *(const f32x4*)(B2 + e2 * DM + c);
    #pragma unroll
    for (int j = 0; j < 4; j++){ b1v[j] = a[j]; b2v[j] = b[j]; }
  }
  f32x4 rr;
  #pragma unroll
  for (int j = 0; j < 4; j++)
    rr[j] = (float)o1[j] + (float)o2[j] + g1 * b1v[j] + g2 * b2v[j];

  if (md){
    bf16x4 ob;
    #pragma unroll
    for (int j = 0; j < 4; j++) ob[j] = (__bf16)rr[j];
    *(bf16x4*)((__bf16*)out + (size_t)t * DM + c) = ob;
  } else {
    *(f32x4*)((float*)out + (size_t)t * DM + c) = rr;
  }
}

extern "C" void kernel_launch(void* const* d_in, const int* in_sizes, int n_in,
                              void* d_out, int out_size, void* d_ws, size_t ws_size,
                              hipStream_t stream)
{
  char* ws = (char*)d_ws;
  int*    meta  = (int*)ws;
  float2* gate2 = (float2*)(ws + WS_GATE2);
  int*    b32   = (int*)(ws + WS_B32);
  int*    top2  = (int*)(ws + WS_TOP2);
  int*    tok   = (int*)(ws + WS_TOK);
  int*    ae    = (int*)(ws + WS_AE);
  float*  agv   = (float*)(ws + WS_AG);
  int*    inv   = (int*)(ws + WS_INV);
  __bf16* conv  = (__bf16*)(ws + WS_CONV);
  __bf16* Hc    = (__bf16*)(ws + WS_HC);
  __bf16* Oc    = (__bf16*)(ws + WS_OC);

  detect_k<<<1, 256, 0, stream>>>(d_in[0], d_in[5], meta, b32);
  convert_k<<<CO_TOT / 1024, 256, 0, stream>>>(
      (const float*)d_in[0], (const float*)d_in[1], (const float*)d_in[2],
      (const float*)d_in[3], (const float*)d_in[4], (const float*)d_in[5],
      (const float*)d_in[6], conv, meta);
  route_k<<<T_TOK / 16, 256, 0, stream>>>(d_in[0], d_in[5], d_in[6], meta,
                                          gate2, top2, b32);
  offsets_k<<<1, 64, 0, stream>>>(meta, b32);
  place_k<<<T_TOK / 256, 256, 0, stream>>>(top2, gate2, b32, tok, ae, agv, inv);
  gemm1g_k<<<dim3(136, 8), 256, 0, stream>>>(d_in[0], d_in[1], d_in[2], conv,
                                             meta, tok, agv, Hc);
  gemm2g_k<<<dim3(136, 16), 256, 0, stream>>>(Hc, d_in[3], conv, meta, Oc);
  combine_k<<<T_TOK, 256, 0, stream>>>(Oc, inv, ae, agv, d_in[4], meta, d_out);
}

// Round 9
// 247.162 us; speedup vs baseline: 1.3572x; 1.2152x over previous
//
#include <hip/hip_runtime.h>
#include <hip/hip_bf16.h>
#include <math.h>

#define T_TOK 8192
#define DM 1024
#define DE 512
#define NE 8
#define DFF 4096

// converted/derived bf16 buffer layout (element offsets inside conv)
#define CO_X   0
#define CO_W1  8388608   // w1T [8][512][1024]  (always written by transp_k)
#define CO_W2  12582912  // w2T [8][1024][512]
#define CO_B1  16777216
#define CO_B2  16781312
#define CO_CE  16789504
#define CO_WR  16797696
#define CO_TOT 16805888

// workspace byte offsets
// meta ints: [0]=flag, [16..23]=counts, [32..39]=off, [48..55]=cinv (floats)
#define WS_GATE2 256
#define WS_B32   65792
#define WS_TOP2  262400
#define WS_TOK   295168
#define WS_AE    360704
#define WS_AG    426240
#define WS_INV   491776
#define WS_CONV  557312
#define WS_HC    34169088
#define WS_OC    50946304

typedef __attribute__((ext_vector_type(8))) __bf16 bf16x8;
typedef __attribute__((ext_vector_type(4))) __bf16 bf16x4;
typedef __attribute__((ext_vector_type(4))) float f32x4;

__device__ __forceinline__ f32x4 ld4(const void* p, size_t off, int md)
{
  f32x4 r;
  if (md){
    bf16x4 v = *(const bf16x4*)((const __bf16*)p + off);
    #pragma unroll
    for (int j = 0; j < 4; j++) r[j] = (float)v[j];
  } else {
    r = *(const f32x4*)((const float*)p + off);
  }
  return r;
}

// async 16B global -> LDS (dest must be lane-linear: base + lane*16)
__device__ __forceinline__ void async_ld16(const __bf16* g, __bf16* l)
{
  __builtin_amdgcn_global_load_lds(
      (const __attribute__((address_space(1))) unsigned int*)g,
      (__attribute__((address_space(3))) unsigned int*)l, 16, 0, 0);
}

// ---- detect dtype (0=fp32,1=bf16) + centroid inv-norms + zero counts/b32 ----
__global__ __launch_bounds__(256) void detect_k(const void* xp, const void* cp,
                                                int* meta, int* b32)
{
  const int tid = threadIdx.x;
  const float* xf = (const float*)xp;
  int ok = 0;
  for (int i = tid; i < 1024; i += 256){
    float a = fabsf(xf[i]);
    if (a > 1e-8f && a < 100.f) ok++;  // NaN compares false
  }
  __shared__ int cnt;
  __shared__ int flg;
  if (tid == 0) cnt = 0;
  __syncthreads();
  atomicAdd(&cnt, ok);
  __syncthreads();
  if (tid == 0){ flg = (cnt > 512) ? 0 : 1; meta[0] = flg; }
  __syncthreads();
  const int md = flg;

  const int e = tid >> 5, i = tid & 31;
  float ss = 0.f;
  for (int j = 0; j < 32; j++){
    size_t d = (size_t)e * DM + i + j * 32;
    float v = md ? (float)((const __bf16*)cp)[d] : ((const float*)cp)[d];
    ss += v * v;
  }
  #pragma unroll
  for (int m = 1; m < 32; m <<= 1) ss += __shfl_xor(ss, m, 64);
  float* cinv = (float*)(meta + 48);   // bytes 192..223: inside meta region
  if (i == 0) cinv[e] = 1.f / fmaxf(sqrtf(ss), 1e-12f);

  b32[tid] = 0;
  if (tid < 8) meta[16 + tid] = 0;
}

// ---- convert x + b1/b2/ce/wr to bf16 (fp32 mode only) ----------------------
__global__ __launch_bounds__(256) void convert_k(
    const float* __restrict__ x, const float* __restrict__ b1,
    const float* __restrict__ b2, const float* __restrict__ ce,
    const float* __restrict__ wr, __bf16* __restrict__ dst,
    const int* __restrict__ meta)
{
  if (meta[0]) return;
  const size_t i = ((size_t)blockIdx.x * 256 + threadIdx.x) * 4;
  const float* src; size_t doff;
  if (i < 8388608){ src = x + i; doff = CO_X + i; }
  else {
    size_t j = i - 8388608;  // b1(4096) b2(8192) ce(8192) wr(8192)
    doff = CO_B1 + j;
    if      (j < 4096)  src = b1 + j;
    else if (j < 12288) src = b2 + (j - 4096);
    else if (j < 20480) src = ce + (j - 12288);
    else                src = wr + (j - 20480);
  }
  f32x4 v = *(const f32x4*)src;
  bf16x4 o;
  #pragma unroll
  for (int j = 0; j < 4; j++) o[j] = (__bf16)v[j];
  *(bf16x4*)(dst + doff) = o;
}

// ---- transpose w1 -> w1T, w2 -> w2T (bf16 out; handles both src dtypes) ----
__global__ __launch_bounds__(256) void transp_k(
    const void* w1q, const void* w2q, __bf16* __restrict__ conv,
    const int* __restrict__ meta)
{
  const int md = meta[0];
  __shared__ __bf16 tile[32][33];
  const int b = blockIdx.x, tid = threadIdx.x;
  const int ty = tid >> 5, tx = tid & 31;

  const void* src; __bf16* dst; int ldS, ldD, i0, j0; size_t soff, doffb;
  if (b < 4096){                       // w1[e]: [1024][512] -> w1T[e]: [512][1024]
    const int e = b >> 9, t = b & 511; // 32 x 16 tiles
    i0 = (t >> 4) << 5; j0 = (t & 15) << 5;
    ldS = DE; ldD = DM;
    soff = (size_t)e * DM * DE;
    dst = conv + CO_W1; doffb = (size_t)e * DE * DM;
    src = md ? (const void*)((const __bf16*)w1q) : (const void*)((const float*)w1q);
  } else {                             // w2[e]: [512][1024] -> w2T[e]: [1024][512]
    const int e = (b - 4096) >> 9, t = (b - 4096) & 511; // 16 x 32 tiles
    i0 = (t >> 5) << 5; j0 = (t & 31) << 5;
    ldS = DM; ldD = DE;
    soff = (size_t)e * DE * DM;
    dst = conv + CO_W2; doffb = (size_t)e * DM * DE;
    src = md ? (const void*)((const __bf16*)w2q) : (const void*)((const float*)w2q);
  }

  #pragma unroll
  for (int rr = 0; rr < 4; rr++){
    const int r = rr * 8 + ty;
    const size_t s = soff + (size_t)(i0 + r) * ldS + j0 + tx;
    tile[r][tx] = md ? ((const __bf16*)src)[s] : (__bf16)((const float*)src)[s];
  }
  __syncthreads();
  #pragma unroll
  for (int rr = 0; rr < 4; rr++){
    const int r = rr * 8 + ty;
    dst[doffb + (size_t)(j0 + r) * ldD + i0 + tx] = tile[tx][r];
  }
}

// ---- routing: 16 lanes/token, 16 tokens/block --------------------------------
__global__ __launch_bounds__(256) void route_k(
    const void* __restrict__ xp, const void* __restrict__ cp,
    const void* __restrict__ wp, const int* __restrict__ meta,
    float2* __restrict__ gate2, int* __restrict__ top2, int* __restrict__ b32)
{
  const int md = meta[0];
  const float* cinv = (const float*)(meta + 48);
  const int tid = threadIdx.x;
  const int g = tid >> 4, l = tid & 15;
  const int t = blockIdx.x * 16 + g;

  __shared__ int hist[8];
  if (tid < 8) hist[tid] = 0;
  __syncthreads();

  float xx = 0.f, cd[NE], wd[NE];
  #pragma unroll
  for (int e = 0; e < NE; e++){ cd[e] = 0.f; wd[e] = 0.f; }

  const size_t xbase = (size_t)t * DM;
  for (int j = 0; j < 16; j++){
    const int d0 = j * 64 + l * 4;
    f32x4 xv = ld4(xp, xbase + d0, md);
    xx += xv[0]*xv[0] + xv[1]*xv[1] + xv[2]*xv[2] + xv[3]*xv[3];
    #pragma unroll
    for (int e = 0; e < NE; e++){
      f32x4 cv = ld4(cp, (size_t)e * DM + d0, md);
      f32x4 wv = ld4(wp, (size_t)e * DM + d0, md);
      cd[e] += xv[0]*cv[0] + xv[1]*cv[1] + xv[2]*cv[2] + xv[3]*cv[3];
      wd[e] += xv[0]*wv[0] + xv[1]*wv[1] + xv[2]*wv[2] + xv[3]*wv[3];
    }
  }
  #pragma unroll
  for (int m = 1; m < 16; m <<= 1){
    xx += __shfl_xor(xx, m, 64);
    #pragma unroll
    for (int e = 0; e < NE; e++){
      cd[e] += __shfl_xor(cd[e], m, 64);
      wd[e] += __shfl_xor(wd[e], m, 64);
    }
  }

  if (l == 0){
    const float rxn = 1.f / fmaxf(sqrtf(xx), 1e-12f);
    float logits[NE];
    #pragma unroll
    for (int e = 0; e < NE; e++) logits[e] = cd[e] * rxn * cinv[e] + wd[e];
    float m1 = -1e30f; int i1 = 0;
    #pragma unroll
    for (int e = 0; e < NE; e++) if (logits[e] > m1){ m1 = logits[e]; i1 = e; }
    float m2 = -1e30f; int i2 = (i1 == 0) ? 1 : 0;
    #pragma unroll
    for (int e = 0; e < NE; e++)
      if (e != i1 && logits[e] > m2){ m2 = logits[e]; i2 = e; }
    float denom = 0.f, ex1 = 0.f, ex2 = 0.f;
    #pragma unroll
    for (int e = 0; e < NE; e++){
      if (logits[e] >= m2){
        float ee = expf(logits[e] - m1);
        denom += ee;
        if (e == i1) ex1 = ee;
        if (e == i2) ex2 = ee;
      }
    }
    const float inv = 1.f / denom;
    gate2[t] = make_float2(ex1 * inv, ex2 * inv);
    top2[t] = i1 | (i2 << 8);
    atomicAdd(&hist[i1], 1);
    atomicAdd(&hist[i2], 1);
  }
  __syncthreads();
  if (tid < 8) atomicAdd(&b32[(blockIdx.x >> 4) * 8 + tid], hist[tid]);
}

// ---- offsets: prefix over 32x8 block counts -> bases + meta ----------------
__global__ void offsets_k(int* meta, int* b32)
{
  const int l = threadIdx.x;
  int running = 0;
  for (int e = 0; e < NE; e++){
    int v = (l < 32) ? b32[l * 8 + e] : 0;
    int incl = v;
    #pragma unroll
    for (int ofs = 1; ofs < 32; ofs <<= 1){
      int n = __shfl_up(incl, ofs, 64);
      if (l >= ofs) incl += n;
    }
    int tot = __shfl(incl, 31, 64);
    if (l < 32) b32[l * 8 + e] = running + (incl - v);
    if (l == 0){ meta[16 + e] = tot; meta[32 + e] = running; }
    running += tot;
  }
}

// ---- placement via block-local LDS cursors ---------------------------------
__global__ __launch_bounds__(256) void place_k(
    const int* __restrict__ top2, const float2* __restrict__ gate2,
    const int* __restrict__ b32, int* __restrict__ tok, int* __restrict__ ae,
    float* __restrict__ agv, int* __restrict__ inv)
{
  __shared__ int cur[8];
  if (threadIdx.x < 8) cur[threadIdx.x] = b32[blockIdx.x * 8 + threadIdx.x];
  __syncthreads();
  const int t = blockIdx.x * 256 + threadIdx.x;
  const int p = top2[t];
  const float2 gg = gate2[t];
  const int e1 = p & 255, e2 = (p >> 8) & 255;
  const int s1 = atomicAdd(&cur[e1], 1);
  tok[s1] = t; ae[s1] = e1; agv[s1] = gg.x; inv[2 * t] = s1;
  const int s2 = atomicAdd(&cur[e2], 1);
  tok[s2] = t; ae[s2] = e2; agv[s2] = gg.y; inv[2 * t + 1] = s2;
}

// block -> (expert, tile)
__device__ __forceinline__ bool find_tile(const int* meta, int tm,
                                          int& e, int& base, int& valid)
{
  for (e = 0; e < NE; e++){
    const int cnt = meta[16 + e];
    const int nt = (cnt + 127) >> 7;
    if (tm < nt){
      const int r0 = tm << 7;
      base = meta[32 + e] + r0;
      valid = cnt - r0;
      return true;
    }
    tm -= nt;
  }
  return false;
}

// ---- grouped GEMM1 (128x128, m97-style staging): Hc = g*gelu(x@w1_e+b1_e) --
__global__ __launch_bounds__(256) void gemm1g_k(
    const void* xq, const void* b1q, const __bf16* __restrict__ conv,
    const int* __restrict__ meta, const int* __restrict__ tok,
    const float* __restrict__ agv, __bf16* __restrict__ Hc)
{
  const int md = meta[0];
  const __bf16* X  = md ? (const __bf16*)xq : conv + CO_X;
  const __bf16* WT = conv + CO_W1;   // w1T [8][512][1024]
  const __bf16* bb = md ? (const __bf16*)b1q : conv + CO_B1;

  int e, base, valid;
  if (!find_tile(meta, blockIdx.x, e, base, valid)) return;
  const int n0 = blockIdx.y * 128;

  __shared__ __attribute__((aligned(16))) __bf16 As[128 * 32];
  __shared__ __attribute__((aligned(16))) __bf16 Bs[128 * 32];

  const int tid = threadIdx.x;
  const int wv = tid >> 6, lane = tid & 63;
  const int q = lane >> 4, ln = lane & 15;
  const int wm = (wv >> 1) * 64, wn = (wv & 1) * 64;
  f32x4 acc[4][4] = {};

  // staging: lane-linear LDS; thread covers (row = tid>>2, chunk = tid&3)
  const int sr = tid >> 2, sc = (tid & 3) * 8;
  const int t0 = tok[base + ((sr      < valid) ? sr      : 0)];
  const int t1 = tok[base + ((sr + 64 < valid) ? sr + 64 : 0)];
  const __bf16* Ag0 = X + (size_t)t0 * DM + sc;
  const __bf16* Ag1 = X + (size_t)t1 * DM + sc;
  const __bf16* Bg0 = WT + (size_t)e * (DE * DM) + (size_t)(n0 + sr) * DM + sc;
  const __bf16* Bg1 = Bg0 + (size_t)64 * DM;

  for (int k0 = 0; k0 < DM; k0 += 32){
    __syncthreads();
    async_ld16(Ag0 + k0, As + tid * 8);
    async_ld16(Ag1 + k0, As + 2048 + tid * 8);
    async_ld16(Bg0 + k0, Bs + tid * 8);
    async_ld16(Bg1 + k0, Bs + 2048 + tid * 8);
    __syncthreads();

    bf16x8 af[4], bf[4];
    #pragma unroll
    for (int mi = 0; mi < 4; mi++)
      af[mi] = *(const bf16x8*)&As[(wm + mi * 16 + ln) * 32 + q * 8];
    #pragma unroll
    for (int ni = 0; ni < 4; ni++)
      bf[ni] = *(const bf16x8*)&Bs[(wn + ni * 16 + ln) * 32 + q * 8];
    #pragma unroll
    for (int mi = 0; mi < 4; mi++)
      #pragma unroll
      for (int ni = 0; ni < 4; ni++)
        acc[mi][ni] = __builtin_amdgcn_mfma_f32_16x16x32_bf16(
            af[mi], bf[ni], acc[mi][ni], 0, 0, 0);
  }

  const int coln = n0 + wn;
  float bset[4];
  #pragma unroll
  for (int ni = 0; ni < 4; ni++)
    bset[ni] = (float)bb[e * DE + coln + ni * 16 + ln];
  #pragma unroll
  for (int mi = 0; mi < 4; mi++){
    #pragma unroll
    for (int r = 0; r < 4; r++){
      const int row = wm + mi * 16 + q * 4 + r;
      if (row < valid){
        const int slot = base + row;
        const float g = agv[slot];
        #pragma unroll
        for (int ni = 0; ni < 4; ni++){
          float v = acc[mi][ni][r] + bset[ni];
          float h = 0.5f * v * (1.0f + erff(v * 0.70710678118654752f));
          Hc[(size_t)slot * DE + coln + ni * 16 + ln] = (__bf16)(g * h);
        }
      }
    }
  }
}

// ---- grouped GEMM2 (128x128, m97-style staging): Oc = Hc @ w2_e ------------
__global__ __launch_bounds__(256) void gemm2g_k(
    const __bf16* __restrict__ Hc, const __bf16* __restrict__ conv,
    const int* __restrict__ meta, __bf16* __restrict__ Oc)
{
  const __bf16* WT = conv + CO_W2;   // w2T [8][1024][512]

  int e, base, valid;
  if (!find_tile(meta, blockIdx.x, e, base, valid)) return;
  const int n0 = blockIdx.y * 128;

  __shared__ __attribute__((aligned(16))) __bf16 As[128 * 32];
  __shared__ __attribute__((aligned(16))) __bf16 Bs[128 * 32];

  const int tid = threadIdx.x;
  const int wv = tid >> 6, lane = tid & 63;
  const int q = lane >> 4, ln = lane & 15;
  const int wm = (wv >> 1) * 64, wn = (wv & 1) * 64;
  f32x4 acc[4][4] = {};

  const int sr = tid >> 2, sc = (tid & 3) * 8;
  const int r0 = (sr      < valid) ? sr      : 0;
  const int r1 = (sr + 64 < valid) ? sr + 64 : 0;
  const __bf16* Ag0 = Hc + (size_t)(base + r0) * DE + sc;
  const __bf16* Ag1 = Hc + (size_t)(base + r1) * DE + sc;
  const __bf16* Bg0 = WT + (size_t)e * (DM * DE) + (size_t)(n0 + sr) * DE + sc;
  const __bf16* Bg1 = Bg0 + (size_t)64 * DE;

  for (int k0 = 0; k0 < DE; k0 += 32){
    __syncthreads();
    async_ld16(Ag0 + k0, As + tid * 8);
    async_ld16(Ag1 + k0, As + 2048 + tid * 8);
    async_ld16(Bg0 + k0, Bs + tid * 8);
    async_ld16(Bg1 + k0, Bs + 2048 + tid * 8);
    __syncthreads();

    bf16x8 af[4], bf[4];
    #pragma unroll
    for (int mi = 0; mi < 4; mi++)
      af[mi] = *(const bf16x8*)&As[(wm + mi * 16 + ln) * 32 + q * 8];
    #pragma unroll
    for (int ni = 0; ni < 4; ni++)
      bf[ni] = *(const bf16x8*)&Bs[(wn + ni * 16 + ln) * 32 + q * 8];
    #pragma unroll
    for (int mi = 0; mi < 4; mi++)
      #pragma unroll
      for (int ni = 0; ni < 4; ni++)
        acc[mi][ni] = __builtin_amdgcn_mfma_f32_16x16x32_bf16(
            af[mi], bf[ni], acc[mi][ni], 0, 0, 0);
  }

  #pragma unroll
  for (int mi = 0; mi < 4; mi++){
    #pragma unroll
    for (int r = 0; r < 4; r++){
      const int row = wm + mi * 16 + q * 4 + r;
      if (row < valid){
        const int slot = base + row;
        #pragma unroll
        for (int ni = 0; ni < 4; ni++)
          Oc[(size_t)slot * DM + n0 + wn + ni * 16 + ln] = (__bf16)acc[mi][ni][r];
      }
    }
  }
}

// ---- combine: out[t] = Oc[s1] + Oc[s2] + g1*b2[e1] + g2*b2[e2] -------------
__global__ __launch_bounds__(256) void combine_k(
    const __bf16* __restrict__ Oc, const int* __restrict__ inv,
    const int* __restrict__ ae, const float* __restrict__ agv,
    const void* b2q, const int* __restrict__ meta, void* out)
{
  const int md = meta[0];
  const int t = blockIdx.x;
  const int s1 = inv[2 * t], s2 = inv[2 * t + 1];
  const int e1 = ae[s1], e2 = ae[s2];
  const float g1 = agv[s1], g2 = agv[s2];
  const int c = threadIdx.x * 4;

  bf16x4 o1 = *(const bf16x4*)(Oc + (size_t)s1 * DM + c);
  bf16x4 o2 = *(const bf16x4*)(Oc + (size_t)s2 * DM + c);
  f32x4 bv1 = ld4(b2q, (size_t)e1 * DM + c, md);
  f32x4 bv2 = ld4(b2q, (size_t)e2 * DM + c, md);
  f32x4 rr;
  #pragma unroll
  for (int j = 0; j < 4; j++)
    rr[j] = (float)o1[j] + (float)o2[j] + g1 * bv1[j] + g2 * bv2[j];

  if (md){
    bf16x4 ob;
    #pragma unroll
    for (int j = 0; j < 4; j++) ob[j] = (__bf16)rr[j];
    *(bf16x4*)((__bf16*)out + (size_t)t * DM + c) = ob;
  } else {
    *(f32x4*)((float*)out + (size_t)t * DM + c) = rr;
  }
}

extern "C" void kernel_launch(void* const* d_in, const int* in_sizes, int n_in,
                              void* d_out, int out_size, void* d_ws, size_t ws_size,
                              hipStream_t stream)
{
  char* ws = (char*)d_ws;
  int*    meta  = (int*)ws;
  float2* gate2 = (float2*)(ws + WS_GATE2);
  int*    b32   = (int*)(ws + WS_B32);
  int*    top2  = (int*)(ws + WS_TOP2);
  int*    tok   = (int*)(ws + WS_TOK);
  int*    ae    = (int*)(ws + WS_AE);
  float*  agv   = (float*)(ws + WS_AG);
  int*    inv   = (int*)(ws + WS_INV);
  __bf16* conv  = (__bf16*)(ws + WS_CONV);
  __bf16* Hc    = (__bf16*)(ws + WS_HC);
  __bf16* Oc    = (__bf16*)(ws + WS_OC);

  detect_k<<<1, 256, 0, stream>>>(d_in[0], d_in[5], meta, b32);
  transp_k<<<8192, 256, 0, stream>>>(d_in[1], d_in[3], conv, meta);
  convert_k<<<8220, 256, 0, stream>>>(
      (const float*)d_in[0], (const float*)d_in[2], (const float*)d_in[4],
      (const float*)d_in[5], (const float*)d_in[6], conv, meta);
  route_k<<<T_TOK / 16, 256, 0, stream>>>(d_in[0], d_in[5], d_in[6], meta,
                                          gate2, top2, b32);
  offsets_k<<<1, 64, 0, stream>>>(meta, b32);
  place_k<<<T_TOK / 256, 256, 0, stream>>>(top2, gate2, b32, tok, ae, agv, inv);
  gemm1g_k<<<dim3(136, 4), 256, 0, stream>>>(d_in[0], d_in[2], conv, meta,
                                             tok, agv, Hc);
  gemm2g_k<<<dim3(136, 8), 256, 0, stream>>>(Hc, conv, meta, Oc);
  combine_k<<<T_TOK, 256, 0, stream>>>(Oc, inv, ae, agv, d_in[4], meta, d_out);
}